// Round 3
// baseline (597.310 us; speedup 1.0000x reference)
//
#include <hip/hip_runtime.h>
#include <hip/hip_fp16.h>

#define N_NODES 10000
#define BATCH   8
#define RCAP    96             // fixed per-row edge capacity (P(deg>96) ~ 1e-18)
#define STR     (N_NODES * 64) // uints per stripe (640,000)
#define NBLK    1024
#define NTHR    256

typedef unsigned int uint;
typedef unsigned short ushort;
typedef __attribute__((ext_vector_type(8))) _Float16 half8;
typedef __attribute__((ext_vector_type(4))) float float4v;
typedef __attribute__((ext_vector_type(2))) uint uint2v;

// ---- numeric helpers -------------------------------------------------------
__device__ inline uint f2bf_bits(float f) {          // edge vals: bf16 in hi16
    uint u = __float_as_uint(f);
    uint r = ((u >> 16) & 1u) + 0x7FFFu;
    return (u + r) >> 16;
}
__device__ inline uint pack2h(float a, float b) {    // x tensors: packed fp16
    return (uint)__half_as_ushort(__float2half(a)) |
           ((uint)__half_as_ushort(__float2half(b)) << 16);
}
__device__ inline float h_lo(uint u) {
    return __half2float(__ushort_as_half((ushort)(u & 0xFFFFu)));
}
__device__ inline float h_hi(uint u) {
    return __half2float(__ushort_as_half((ushort)(u >> 16)));
}

// ---- grid barrier (all NBLK blocks resident by construction) ---------------
// Monotonic counter in ws (memset to 0 each launch). Release fence ->
// device-scope atomicAdd -> relaxed spin -> acquire fence. Guide §6 G16.
__device__ __forceinline__ void grid_barrier(int* bar, int target) {
    __syncthreads();
    if (threadIdx.x == 0) {
        __threadfence();                               // release (wb L2)
        atomicAdd(bar, 1);                             // device scope
        while (__hip_atomic_load(bar, __ATOMIC_RELAXED,
                                 __HIP_MEMORY_SCOPE_AGENT) < target)
            __builtin_amdgcn_s_sleep(2);
        __threadfence();                               // acquire (inv L1/L2)
    }
    __syncthreads();
}

// ---- spmm inner machinery (2-deep pipeline, SALU edge decode) --------------
#define LOADE(EP, OFF)                                                        \
    _Pragma("unroll") for (int jj = 0; jj < 8; ++jj) EP[jj] = edges[(OFF) + jj];

#define GATHERX(XR, EP)                                                       \
    _Pragma("unroll") for (int jj = 0; jj < 8; ++jj) {                        \
        uint c = EP[jj] & 0x3FFFu;                                            \
        if (c > N_NODES - 1) c = N_NODES - 1; /* s_min (poisoned slots) */    \
        XR[jj] = xq[c * 64u + lane];          /* SALU idx + saddr gather */   \
    }

#define FMA8(EP, XR, G0)                                                      \
    _Pragma("unroll") for (int jj = 0; jj < 8; ++jj) {                        \
        uint vb = ((G0) + jj < cnt) ? (EP[jj] & 0xFFFF0000u) : 0u; /* SALU */ \
        float vj = __uint_as_float(vb);                                       \
        a0 += vj * h_lo(XR[jj]); /* v_fma_mix_f32 */                          \
        a1 += vj * h_hi(XR[jj]); /* v_fma_mix_f32 */                          \
    }

__device__ __forceinline__ void spmm_phase(
    const int* __restrict__ cursor, const uint* __restrict__ edges,
    const uint* __restrict__ xin, uint* __restrict__ xout,
    const uint* __restrict__ xsub, float scale,
    int B, int wave, uint lane)
{
    int q = (B & 7) >> 1;                  // stripe pinned to XCD pair {2q,2q+1}
    const uint* xq = xin + (size_t)q * STR;
    for (int j = (B >> 3); j < 1250; j += 128) {   // each j: 4 rows (1/wave)
        int row  = (2 * j + (B & 1)) * 4 + wave;
        int base = __builtin_amdgcn_readfirstlane(row * RCAP);
        int cnt  = __builtin_amdgcn_readfirstlane(cursor[row]);
        int nblk = (cnt + 7) >> 3;         // >= 1 (diagonal)

        uint sx = 0;                        // hoisted subtract operand
        if (xsub) sx = xsub[(size_t)q * STR + (size_t)row * 64 + lane];

        float a0 = 0.f, a1 = 0.f;
        uint epA[8], epB[8], xA[8], xB[8];
        LOADE(epA, base);
        GATHERX(xA, epA);
        int k = 0;
        for (; k + 2 <= nblk; k += 2) {
            LOADE(epB, base + 8 * (k + 1));
            GATHERX(xB, epB);
            FMA8(epA, xA, 8 * k);
            if (k + 2 < nblk) {
                LOADE(epA, base + 8 * (k + 2));
                GATHERX(xA, epA);
            }
            FMA8(epB, xB, 8 * (k + 1));
        }
        if (k < nblk) FMA8(epA, xA, 8 * k);

        float o0 = scale * a0, o1 = scale * a1;
        if (xsub) { o0 -= h_lo(sx); o1 -= h_hi(sx); }
        // plain store: keep the line dirty in THIS XCD pair's L2 (consumer
        // of stripe q is pinned here) -- nontemporal dropped deliberately.
        xout[(size_t)q * STR + (size_t)row * 64 + lane] = pack2h(o0, o1);
    }
}

// ---------------------------------------------------------------------------
// k_fused: all four phases in one persistent kernel, grid barriers between.
// 1024 blocks x 256 thr, __launch_bounds__(256,4) -> 4 blocks/CU resident
// (LDS 25.6KB -> 6/CU cap; VGPR capped at 128). Work item L == B (mod 1024)
// preserves L&7 = B&7 -> stripe/batch pinning consistent across ALL phases:
// x1/x2 stripe-q lines are produced AND consumed on XCD pair {2q,2q+1}.
// ---------------------------------------------------------------------------
__global__ __launch_bounds__(NTHR, 4) void k_fused(
    const float4v* __restrict__ in4,
    const int* __restrict__ rows, const int* __restrict__ cols,
    const float* __restrict__ vals,
    const float* __restrict__ W, const float* __restrict__ bias,
    uint* __restrict__ x0, uint* __restrict__ x1, uint* __restrict__ x2,
    int* __restrict__ cursor, uint* __restrict__ edges,
    int* __restrict__ bar, float* __restrict__ out, int nnz)
{
    __shared__ ushort sWt[64][200];        // combine weights [u][k], 25.6 KB
    const int B    = blockIdx.x;
    const int t    = threadIdx.x;
    const int wave = t >> 6;
    const uint lane = t & 63;

    // ---- phase 1: transpose fp32->fp16 stripes + edge scatter --------------
    for (int gid = B * NTHR + t; gid < N_NODES * 128; gid += NBLK * NTHR) {
        if (gid < nnz) {
            int r   = rows[gid];
            int pos = r * RCAP + atomicAdd(&cursor[r], 1);
            edges[pos] = (uint)cols[gid] | (f2bf_bits(vals[gid]) << 16);
        }
        int i4 = gid & 15;
        int b  = (gid >> 4) & 7;
        int n  = gid >> 7;
        float4v v = __builtin_nontemporal_load(
            &in4[((size_t)b * N_NODES + n) * 16 + i4]);
        int c_u = b * 32 + i4 * 2;
        int q   = c_u >> 6;
        uint2v pk;
        pk.x = pack2h(v.x, v.y);
        pk.y = pack2h(v.z, v.w);
        *(uint2v*)(x0 + (size_t)q * STR + (size_t)n * 64 + (c_u & 63)) = pk;
    }
    grid_barrier(bar, NBLK);

    // ---- phase 2: x1 = L x0 ------------------------------------------------
    spmm_phase(cursor, edges, x0, x1, nullptr, 1.0f, B, wave, lane);
    grid_barrier(bar, 2 * NBLK);

    // ---- phase 3: x2 = 2 L x1 - x0 -----------------------------------------
    spmm_phase(cursor, edges, x1, x2, x0, 2.0f, B, wave, lane);
    grid_barrier(bar, 3 * NBLK);

    // ---- phase 4: combine (MFMA f16) ---------------------------------------
    for (int e = t; e < 192 * 64; e += NTHR) {
        int f = e >> 6, u = e & 63;
        int i = f / 3, m = f - 3 * i;
        sWt[u][m * 64 + i] = __half_as_ushort(__float2half(W[e]));
    }
    __syncthreads();

    int mrow = lane & 15, quad = lane >> 4;
    int b = B & 7;                          // batch pinned -> stripe b>>1
    const uint* xs[3] = {x0, x1, x2};
    for (int m = (B >> 3); m < 157; m += 128) {   // 1256 virtual blocks
        int n0 = m * 64 + wave * 16;
        int an = n0 + mrow;
        if (an > N_NODES - 1) an = N_NODES - 1;

        half8 af[6];
#pragma unroll
        for (int kb = 0; kb < 6; ++kb) {
            int mat = kb >> 1;
            int c_u = b * 32 + (kb & 1) * 16 + quad * 4;
            int q   = c_u >> 6;             // = b>>1
            af[kb] = *(const half8*)(xs[mat] + (size_t)q * STR +
                                     (size_t)an * 64 + (c_u & 63));
        }

        float4v acc[4];
#pragma unroll
        for (int ut = 0; ut < 4; ++ut) acc[ut] = (float4v){0.f, 0.f, 0.f, 0.f};
#pragma unroll
        for (int kb = 0; kb < 6; ++kb)
#pragma unroll
            for (int ut = 0; ut < 4; ++ut)
                acc[ut] = __builtin_amdgcn_mfma_f32_16x16x32_f16(
                    af[kb],
                    *(const half8*)&sWt[ut * 16 + mrow][kb * 32 + quad * 8],
                    acc[ut], 0, 0, 0);

#pragma unroll
        for (int ut = 0; ut < 4; ++ut) {
            float bv = bias[ut * 16 + mrow];
            int u = ut * 16 + mrow;
#pragma unroll
            for (int r = 0; r < 4; ++r) {
                int n = n0 + quad * 4 + r;
                if (n < N_NODES)
                    __builtin_nontemporal_store(acc[ut][r] + bv,
                        &out[((size_t)b * N_NODES + n) * 64 + u]);
            }
        }
    }
}

// ---------------------------------------------------------------------------
extern "C" void kernel_launch(void* const* d_in, const int* in_sizes, int n_in,
                              void* d_out, int out_size, void* d_ws, size_t ws_size,
                              hipStream_t stream) {
    const float* inputs = (const float*)d_in[0];
    const int*   rows   = (const int*)d_in[1];
    const int*   cols   = (const int*)d_in[2];
    const float* vals   = (const float*)d_in[3];
    const float* W      = (const float*)d_in[4];
    const float* bias   = (const float*)d_in[5];
    float*       out    = (float*)d_out;
    int nnz = in_sizes[1];

    char* p = (char*)d_ws;
    auto alloc = [&](size_t bytes) {
        char* r = p;
        p += (bytes + 255) & ~(size_t)255;
        return r;
    };
    uint* x0     = (uint*)alloc(sizeof(uint) * (size_t)N_NODES * 256);
    uint* x1     = (uint*)alloc(sizeof(uint) * (size_t)N_NODES * 256);
    uint* x2     = (uint*)alloc(sizeof(uint) * (size_t)N_NODES * 256);
    int*  cursor = (int*)alloc(sizeof(int) * (N_NODES + 64));
    uint* edges  = (uint*)alloc(sizeof(uint) * (size_t)N_NODES * RCAP);
    int*  bar    = cursor + N_NODES;

    (void)hipMemsetAsync(cursor, 0, sizeof(int) * (N_NODES + 64), stream);
    k_fused<<<NBLK, NTHR, 0, stream>>>((const float4v*)inputs, rows, cols,
                                       vals, W, bias, x0, x1, x2, cursor,
                                       edges, bar, out, nnz);
}

// Round 5
// 287.741 us; speedup vs baseline: 2.0759x; 2.0759x over previous
//
#include <hip/hip_runtime.h>
#include <hip/hip_fp16.h>

#define N_NODES 10000
#define BATCH   8
#define IN_SZ   64
#define UNITS   64
#define ROW_U   256            // uints per f16 row (512 f16 = 4 stripes of 64)
#define RCAP    96             // fixed per-row edge capacity (P(deg>96) ~ 1e-18)
#define STR     (N_NODES * 64) // uints per stripe (640,000)

typedef unsigned int uint;
typedef unsigned short ushort;
typedef __attribute__((ext_vector_type(8))) _Float16 half8;
typedef __attribute__((ext_vector_type(4))) float float4v;
typedef __attribute__((ext_vector_type(2))) float float2v;

// ---- numeric helpers -------------------------------------------------------
// Edge values bf16-packed (high 16 bits ARE the fp32 bits -> SALU decode).
__device__ inline uint f2bf_bits(float f) {
    uint u = __float_as_uint(f);
    uint r = ((u >> 16) & 1u) + 0x7FFFu;
    return (u + r) >> 16;
}
// x tensors stored as packed fp16 (RNE): enables v_fma_mix_f32 in spmm loop.
__device__ inline uint pack2h(float a, float b) {
    return (uint)__half_as_ushort(__float2half(a)) |
           ((uint)__half_as_ushort(__float2half(b)) << 16);
}
__device__ inline float h_lo(uint u) {
    return __half2float(__ushort_as_half((ushort)(u & 0xFFFFu)));
}
__device__ inline float h_hi(uint u) {
    return __half2float(__ushort_as_half((ushort)(u >> 16)));
}

// ---------------------------------------------------------------------------
// MEASUREMENT ROUND (retry of r4 with launch configs matching kernel bodies:
// k_spmm and k_combine are 1-D-grid kernels; r4 mistakenly launched them 2-D,
// leaving 3/4 of rows unprocessed -> poison -> absmax 5.09).
// This file == Round-1 kernel (best measured, 181.35us) with the ENTIRE
// pipeline launched twice (idempotent: pass 2 re-zeroes cursor, rebuilds the
// same per-row edge multiset, rewrites x0/x1/x2/out with identical values).
// dur_us - 181.4 == true total kernel time K, resolving whether harness fixed
// overhead F is ~57us (K~124, headroom) or ~120us (K~60, near traffic floor).
// ---------------------------------------------------------------------------

// ---------------------------------------------------------------------------
// k_transpose_scatter: transpose in[b,n,i] fp32 -> x0 stripe layout fp16;
// scatter COO edges into fixed 96-slot row buckets as PACKED 4-byte records:
// low 14 bits = col, high 16 bits = val as bf16 (bit pattern of fp32>>16).
// Grid: <<<N_NODES, 256>>> (1-D, 2.56M threads).
// ---------------------------------------------------------------------------
__global__ __launch_bounds__(256) void k_transpose_scatter(
    const float2v* __restrict__ in2, uint* __restrict__ x0,
    const int* __restrict__ rows, const int* __restrict__ cols,
    const float* __restrict__ vals, int* __restrict__ cursor,
    uint* __restrict__ edges, int nnz) {
    int gid = blockIdx.x * 256 + threadIdx.x;      // 2,560,000 total
    if (gid < nnz) {
        int r   = rows[gid];
        int pos = r * RCAP + atomicAdd(&cursor[r], 1);
        edges[pos] = (uint)cols[gid] | (f2bf_bits(vals[gid]) << 16);
    }
    int n  = gid >> 8;          // node
    int b  = (gid >> 5) & 7;    // batch
    int iu = gid & 31;
    float2v v = __builtin_nontemporal_load(&in2[(size_t)b * (N_NODES * 32) +
                                                (size_t)n * 32 + iu]);
    int q = (gid >> 6) & 3;     // stripe
    x0[(size_t)q * STR + (size_t)n * 64 + (gid & 63)] = pack2h(v.x, v.y);
}

// ---------------------------------------------------------------------------
// k_spmm: one WAVE per (row, stripe); lane owns one uint (2 fp16 cols).
// fp16 x storage -> inner loop is 2x v_fma_mix_f32 per uint per edge.
// XCD-pinned stripes: stripe q only on XCDs {2q,2q+1} (2.56MB < 4MB L2).
// Grid: <<<N_NODES, 256>>> (1-D; L&7 encodes stripe + row-block parity).
// ---------------------------------------------------------------------------
__global__ __launch_bounds__(256) void k_spmm(const int* __restrict__ cursor,
                                              const uint* __restrict__ edges,
                                              const uint* __restrict__ xin,
                                              uint* __restrict__ xout,
                                              const uint* __restrict__ xsub,
                                              float scale) {
    int L    = blockIdx.x;              // 10000 blocks
    int q    = (L & 7) >> 1;            // stripe pinned to XCD pair {2q,2q+1}
    int rb   = ((L >> 3) << 1) | (L & 1);   // 0..2499, bijective per stripe
    int wave = threadIdx.x >> 6;
    uint lane = threadIdx.x & 63;
    int row  = rb * 4 + wave;

    const uint* xq = xin + (size_t)q * STR;
    int base = row * RCAP;
    int cnt  = __builtin_amdgcn_readfirstlane(cursor[row]);

    float a0 = 0.f, a1 = 0.f;

    int full_end = base + (cnt & ~7);
    int e = base;
    for (; e < full_end; e += 8) {
        uint ep[8];
#pragma unroll
        for (int j = 0; j < 8; ++j) ep[j] = edges[e + j];   // uniform -> s_load
        uint x[8];
#pragma unroll
        for (int j = 0; j < 8; ++j)
            x[j] = xq[(ep[j] & 0x3FFFu) * 64u + lane];      // SALU idx, saddr
#pragma unroll
        for (int j = 0; j < 8; ++j) {
            float vj = __uint_as_float(ep[j] & 0xFFFF0000u); // SALU: bf16->f32
            a0 += vj * h_lo(x[j]);                           // v_fma_mix_f32
            a1 += vj * h_hi(x[j]);                           // v_fma_mix_f32
        }
    }
    int rem = cnt & 7;
    if (rem) {
        uint ep[8];
#pragma unroll
        for (int j = 0; j < 8; ++j) ep[j] = edges[e + j];
        uint x[8];
#pragma unroll
        for (int j = 0; j < 8; ++j) {
            uint c = ep[j] & 0x3FFFu;
            if (c > N_NODES - 1) c = N_NODES - 1;            // s_min (poison)
            x[j] = xq[c * 64u + lane];
        }
#pragma unroll
        for (int j = 0; j < 8; ++j) {
            float vj = (j < rem) ? __uint_as_float(ep[j] & 0xFFFF0000u) : 0.f;
            a0 += vj * h_lo(x[j]);
            a1 += vj * h_hi(x[j]);
        }
    }

    float o0 = scale * a0, o1 = scale * a1;
    if (xsub) {
        uint sx = __builtin_nontemporal_load(
            &xsub[(size_t)q * STR + (size_t)row * 64 + lane]);
        o0 -= h_lo(sx);
        o1 -= h_hi(sx);
    }
    __builtin_nontemporal_store(pack2h(o0, o1),
        &xout[(size_t)q * STR + (size_t)row * 64 + lane]);
}

// ---------------------------------------------------------------------------
// k_combine (MFMA f16): out[b,n,u] = bias[u] + sum_k A[(b,n), k] * Wp[k, u].
// Grid: <<<157*8, 256>>> (1-D); b = L&7 pins batch -> stripe q=b>>1 stays on
// XCD pair {2q,2q+1} (matches spmm write locality).
// ---------------------------------------------------------------------------
__global__ __launch_bounds__(256) void k_combine(const uint* __restrict__ x0,
                                                 const uint* __restrict__ x1,
                                                 const uint* __restrict__ x2,
                                                 const float* __restrict__ W,
                                                 const float* __restrict__ bias,
                                                 float* __restrict__ out) {
    __shared__ ushort sWt[64][200];    // [u][k] f16, pad 192->200 (25.6 KB)
    int t = threadIdx.x;
    for (int e = t; e < 192 * 64; e += 256) {
        int f = e >> 6;                // fan_in row = i*3 + m
        int u = e & 63;
        int i = f / 3;
        int m = f - 3 * i;
        sWt[u][m * 64 + i] = __half_as_ushort(__float2half(W[e]));
    }
    __syncthreads();

    int wave = t >> 6, lane = t & 63;
    int mrow = lane & 15, quad = lane >> 4;
    int L    = blockIdx.x;
    int b    = L & 7;                  // XCD-pinned batch -> stripe b>>1
    int n0   = (L >> 3) * 64 + wave * 16;

    const uint* xs[3] = {x0, x1, x2};
    int an = n0 + mrow;
    if (an > N_NODES - 1) an = N_NODES - 1;    // clamp tail reads

    half8 af[6];
#pragma unroll
    for (int kb = 0; kb < 6; ++kb) {
        int mat = kb >> 1;
        int c_u = b * 32 + (kb & 1) * 16 + quad * 4;      // column uint index
        int q   = c_u >> 6;                               // = b>>1
        af[kb] = __builtin_nontemporal_load(
            (const half8*)(xs[mat] + (size_t)q * STR + (size_t)an * 64 +
                           (c_u & 63)));
    }

    float4v acc[4];
#pragma unroll
    for (int ut = 0; ut < 4; ++ut) acc[ut] = (float4v){0.f, 0.f, 0.f, 0.f};

#pragma unroll
    for (int kb = 0; kb < 6; ++kb)
#pragma unroll
        for (int ut = 0; ut < 4; ++ut)
            acc[ut] = __builtin_amdgcn_mfma_f32_16x16x32_f16(
                af[kb],
                *(const half8*)&sWt[ut * 16 + mrow][kb * 32 + quad * 8],
                acc[ut], 0, 0, 0);

#pragma unroll
    for (int ut = 0; ut < 4; ++ut) {
        float bv = bias[ut * 16 + mrow];
        int u = ut * 16 + mrow;
#pragma unroll
        for (int r = 0; r < 4; ++r) {
            int n = n0 + quad * 4 + r;
            if (n < N_NODES)
                __builtin_nontemporal_store(acc[ut][r] + bv,
                    &out[((size_t)b * N_NODES + n) * UNITS + u]);
        }
    }
}

// ---------------------------------------------------------------------------
extern "C" void kernel_launch(void* const* d_in, const int* in_sizes, int n_in,
                              void* d_out, int out_size, void* d_ws, size_t ws_size,
                              hipStream_t stream) {
    const float* inputs = (const float*)d_in[0];
    const int*   rows   = (const int*)d_in[1];
    const int*   cols   = (const int*)d_in[2];
    const float* vals   = (const float*)d_in[3];
    const float* W      = (const float*)d_in[4];
    const float* bias   = (const float*)d_in[5];
    float*       out    = (float*)d_out;
    int nnz = in_sizes[1];

    char* p = (char*)d_ws;
    auto alloc = [&](size_t bytes) {
        char* r = p;
        p += (bytes + 255) & ~(size_t)255;
        return r;
    };
    uint* x0     = (uint*)alloc(sizeof(uint) * (size_t)N_NODES * ROW_U);
    uint* x1     = (uint*)alloc(sizeof(uint) * (size_t)N_NODES * ROW_U);
    uint* x2     = (uint*)alloc(sizeof(uint) * (size_t)N_NODES * ROW_U);
    int*  cursor = (int*)alloc(sizeof(int) * N_NODES);
    uint* edges  = (uint*)alloc(sizeof(uint) * (size_t)N_NODES * RCAP);

    // --- pipeline, twice (idempotent; pass 2 re-zeroes cursor and rewrites
    // everything with identical values). dur_us - 181.4 == true kernel sum K.
    // ALL GRIDS 1-D, matching the kernel bodies (r4's failure was a 2-D grid
    // mismatch here, not the double-pass itself). ---
    for (int pass = 0; pass < 2; ++pass) {
        (void)hipMemsetAsync(cursor, 0, sizeof(int) * N_NODES, stream);
        k_transpose_scatter<<<N_NODES, 256, 0, stream>>>(
            (const float2v*)inputs, x0, rows, cols, vals, cursor, edges, nnz);
        k_spmm<<<N_NODES, 256, 0, stream>>>(cursor, edges, x0, x1, nullptr,
                                            1.0f);
        k_spmm<<<N_NODES, 256, 0, stream>>>(cursor, edges, x1, x2, x0, 2.0f);
        k_combine<<<157 * 8, 256, 0, stream>>>(x0, x1, x2, W, bias, out);
    }
}

// Round 6
// 282.583 us; speedup vs baseline: 2.1138x; 1.0183x over previous
//
#include <hip/hip_runtime.h>
#include <hip/hip_fp16.h>

#define N_NODES 10000
#define BATCH   8
#define IN_SZ   64
#define UNITS   64
#define ROW_U   256            // uints per f16 row (512 f16 = 4 stripes of 64)
#define RCAP    96             // fixed per-row edge capacity (P(deg>96) ~ 1e-18)
#define STR     (N_NODES * 64) // uints per stripe (640,000)

typedef unsigned int uint;
typedef unsigned short ushort;
typedef __attribute__((ext_vector_type(8))) _Float16 half8;
typedef __attribute__((ext_vector_type(4))) float float4v;
typedef __attribute__((ext_vector_type(2))) float float2v;

// ---- numeric helpers -------------------------------------------------------
// Edge values bf16-packed (high 16 bits ARE the fp32 bits -> SALU decode).
__device__ inline uint f2bf_bits(float f) {
    uint u = __float_as_uint(f);
    uint r = ((u >> 16) & 1u) + 0x7FFFu;
    return (u + r) >> 16;
}
// x tensors stored as packed fp16 (RNE): enables v_fma_mix_f32 in spmm loop.
__device__ inline uint pack2h(float a, float b) {
    return (uint)__half_as_ushort(__float2half(a)) |
           ((uint)__half_as_ushort(__float2half(b)) << 16);
}
__device__ inline float h_lo(uint u) {
    return __half2float(__ushort_as_half((ushort)(u & 0xFFFFu)));
}
__device__ inline float h_hi(uint u) {
    return __half2float(__ushort_as_half((ushort)(u >> 16)));
}

// ---------------------------------------------------------------------------
// MEASUREMENT ROUND 2 (per-kernel split). Established so far (r1 vs r5):
//   K = kernel sum = 106.3us, F = fixed overhead = 75.1us (dispatch-count-
//   independent; fusing won't reduce it).
// This round: single pipeline + 4 EXTRA spmm1 launches (idempotent: spmm1
// reads cursor/edges/x0 only, rewrites x1 with byte-identical values).
//   dur_us = 181.4 + 4 * t_spmm1   ->  t_spmm1 to +-1us.
// With t_spmm2 ~= t_spmm1, this resolves nearly the full split and decides
// whether rounds 7+ attack spmm structure or the transpose/combine pair.
// Kernel bodies are UNCHANGED from the passing r5 file (1-D grids).
// ---------------------------------------------------------------------------

// ---------------------------------------------------------------------------
// k_transpose_scatter: transpose in[b,n,i] fp32 -> x0 stripe layout fp16;
// scatter COO edges into fixed 96-slot row buckets as PACKED 4-byte records:
// low 14 bits = col, high 16 bits = val as bf16 (bit pattern of fp32>>16).
// Grid: <<<N_NODES, 256>>> (1-D, 2.56M threads).
// ---------------------------------------------------------------------------
__global__ __launch_bounds__(256) void k_transpose_scatter(
    const float2v* __restrict__ in2, uint* __restrict__ x0,
    const int* __restrict__ rows, const int* __restrict__ cols,
    const float* __restrict__ vals, int* __restrict__ cursor,
    uint* __restrict__ edges, int nnz) {
    int gid = blockIdx.x * 256 + threadIdx.x;      // 2,560,000 total
    if (gid < nnz) {
        int r   = rows[gid];
        int pos = r * RCAP + atomicAdd(&cursor[r], 1);
        edges[pos] = (uint)cols[gid] | (f2bf_bits(vals[gid]) << 16);
    }
    int n  = gid >> 8;          // node
    int b  = (gid >> 5) & 7;    // batch
    int iu = gid & 31;
    float2v v = __builtin_nontemporal_load(&in2[(size_t)b * (N_NODES * 32) +
                                                (size_t)n * 32 + iu]);
    int q = (gid >> 6) & 3;     // stripe
    x0[(size_t)q * STR + (size_t)n * 64 + (gid & 63)] = pack2h(v.x, v.y);
}

// ---------------------------------------------------------------------------
// k_spmm: one WAVE per (row, stripe); lane owns one uint (2 fp16 cols).
// fp16 x storage -> inner loop is 2x v_fma_mix_f32 per uint per edge.
// XCD-pinned stripes: stripe q only on XCDs {2q,2q+1} (2.56MB < 4MB L2).
// Grid: <<<N_NODES, 256>>> (1-D; L&7 encodes stripe + row-block parity).
// ---------------------------------------------------------------------------
__global__ __launch_bounds__(256) void k_spmm(const int* __restrict__ cursor,
                                              const uint* __restrict__ edges,
                                              const uint* __restrict__ xin,
                                              uint* __restrict__ xout,
                                              const uint* __restrict__ xsub,
                                              float scale) {
    int L    = blockIdx.x;              // 10000 blocks
    int q    = (L & 7) >> 1;            // stripe pinned to XCD pair {2q,2q+1}
    int rb   = ((L >> 3) << 1) | (L & 1);   // 0..2499, bijective per stripe
    int wave = threadIdx.x >> 6;
    uint lane = threadIdx.x & 63;
    int row  = rb * 4 + wave;

    const uint* xq = xin + (size_t)q * STR;
    int base = row * RCAP;
    int cnt  = __builtin_amdgcn_readfirstlane(cursor[row]);

    float a0 = 0.f, a1 = 0.f;

    int full_end = base + (cnt & ~7);
    int e = base;
    for (; e < full_end; e += 8) {
        uint ep[8];
#pragma unroll
        for (int j = 0; j < 8; ++j) ep[j] = edges[e + j];   // uniform -> s_load
        uint x[8];
#pragma unroll
        for (int j = 0; j < 8; ++j)
            x[j] = xq[(ep[j] & 0x3FFFu) * 64u + lane];      // SALU idx, saddr
#pragma unroll
        for (int j = 0; j < 8; ++j) {
            float vj = __uint_as_float(ep[j] & 0xFFFF0000u); // SALU: bf16->f32
            a0 += vj * h_lo(x[j]);                           // v_fma_mix_f32
            a1 += vj * h_hi(x[j]);                           // v_fma_mix_f32
        }
    }
    int rem = cnt & 7;
    if (rem) {
        uint ep[8];
#pragma unroll
        for (int j = 0; j < 8; ++j) ep[j] = edges[e + j];
        uint x[8];
#pragma unroll
        for (int j = 0; j < 8; ++j) {
            uint c = ep[j] & 0x3FFFu;
            if (c > N_NODES - 1) c = N_NODES - 1;            // s_min (poison)
            x[j] = xq[c * 64u + lane];
        }
#pragma unroll
        for (int j = 0; j < 8; ++j) {
            float vj = (j < rem) ? __uint_as_float(ep[j] & 0xFFFF0000u) : 0.f;
            a0 += vj * h_lo(x[j]);
            a1 += vj * h_hi(x[j]);
        }
    }

    float o0 = scale * a0, o1 = scale * a1;
    if (xsub) {
        uint sx = __builtin_nontemporal_load(
            &xsub[(size_t)q * STR + (size_t)row * 64 + lane]);
        o0 -= h_lo(sx);
        o1 -= h_hi(sx);
    }
    __builtin_nontemporal_store(pack2h(o0, o1),
        &xout[(size_t)q * STR + (size_t)row * 64 + lane]);
}

// ---------------------------------------------------------------------------
// k_combine (MFMA f16): out[b,n,u] = bias[u] + sum_k A[(b,n), k] * Wp[k, u].
// Grid: <<<157*8, 256>>> (1-D); b = L&7 pins batch -> stripe q=b>>1 stays on
// XCD pair {2q,2q+1} (matches spmm write locality).
// ---------------------------------------------------------------------------
__global__ __launch_bounds__(256) void k_combine(const uint* __restrict__ x0,
                                                 const uint* __restrict__ x1,
                                                 const uint* __restrict__ x2,
                                                 const float* __restrict__ W,
                                                 const float* __restrict__ bias,
                                                 float* __restrict__ out) {
    __shared__ ushort sWt[64][200];    // [u][k] f16, pad 192->200 (25.6 KB)
    int t = threadIdx.x;
    for (int e = t; e < 192 * 64; e += 256) {
        int f = e >> 6;                // fan_in row = i*3 + m
        int u = e & 63;
        int i = f / 3;
        int m = f - 3 * i;
        sWt[u][m * 64 + i] = __half_as_ushort(__float2half(W[e]));
    }
    __syncthreads();

    int wave = t >> 6, lane = t & 63;
    int mrow = lane & 15, quad = lane >> 4;
    int L    = blockIdx.x;
    int b    = L & 7;                  // XCD-pinned batch -> stripe b>>1
    int n0   = (L >> 3) * 64 + wave * 16;

    const uint* xs[3] = {x0, x1, x2};
    int an = n0 + mrow;
    if (an > N_NODES - 1) an = N_NODES - 1;    // clamp tail reads

    half8 af[6];
#pragma unroll
    for (int kb = 0; kb < 6; ++kb) {
        int mat = kb >> 1;
        int c_u = b * 32 + (kb & 1) * 16 + quad * 4;      // column uint index
        int q   = c_u >> 6;                               // = b>>1
        af[kb] = __builtin_nontemporal_load(
            (const half8*)(xs[mat] + (size_t)q * STR + (size_t)an * 64 +
                           (c_u & 63)));
    }

    float4v acc[4];
#pragma unroll
    for (int ut = 0; ut < 4; ++ut) acc[ut] = (float4v){0.f, 0.f, 0.f, 0.f};

#pragma unroll
    for (int kb = 0; kb < 6; ++kb)
#pragma unroll
        for (int ut = 0; ut < 4; ++ut)
            acc[ut] = __builtin_amdgcn_mfma_f32_16x16x32_f16(
                af[kb],
                *(const half8*)&sWt[ut * 16 + mrow][kb * 32 + quad * 8],
                acc[ut], 0, 0, 0);

#pragma unroll
    for (int ut = 0; ut < 4; ++ut) {
        float bv = bias[ut * 16 + mrow];
        int u = ut * 16 + mrow;
#pragma unroll
        for (int r = 0; r < 4; ++r) {
            int n = n0 + quad * 4 + r;
            if (n < N_NODES)
                __builtin_nontemporal_store(acc[ut][r] + bv,
                    &out[((size_t)b * N_NODES + n) * UNITS + u]);
        }
    }
}

// ---------------------------------------------------------------------------
extern "C" void kernel_launch(void* const* d_in, const int* in_sizes, int n_in,
                              void* d_out, int out_size, void* d_ws, size_t ws_size,
                              hipStream_t stream) {
    const float* inputs = (const float*)d_in[0];
    const int*   rows   = (const int*)d_in[1];
    const int*   cols   = (const int*)d_in[2];
    const float* vals   = (const float*)d_in[3];
    const float* W      = (const float*)d_in[4];
    const float* bias   = (const float*)d_in[5];
    float*       out    = (float*)d_out;
    int nnz = in_sizes[1];

    char* p = (char*)d_ws;
    auto alloc = [&](size_t bytes) {
        char* r = p;
        p += (bytes + 255) & ~(size_t)255;
        return r;
    };
    uint* x0     = (uint*)alloc(sizeof(uint) * (size_t)N_NODES * ROW_U);
    uint* x1     = (uint*)alloc(sizeof(uint) * (size_t)N_NODES * ROW_U);
    uint* x2     = (uint*)alloc(sizeof(uint) * (size_t)N_NODES * ROW_U);
    int*  cursor = (int*)alloc(sizeof(int) * N_NODES);
    uint* edges  = (uint*)alloc(sizeof(uint) * (size_t)N_NODES * RCAP);

    (void)hipMemsetAsync(cursor, 0, sizeof(int) * N_NODES, stream);
    k_transpose_scatter<<<N_NODES, 256, 0, stream>>>(
        (const float2v*)inputs, x0, rows, cols, vals, cursor, edges, nnz);

    // spmm1 x5: 4 redundant launches (byte-identical rewrites of x1).
    // dur_us = 181.4 + 4 * t_spmm1  -> per-kernel split.
    for (int rep = 0; rep < 5; ++rep)
        k_spmm<<<N_NODES, 256, 0, stream>>>(cursor, edges, x0, x1, nullptr,
                                            1.0f);
    k_spmm<<<N_NODES, 256, 0, stream>>>(cursor, edges, x1, x2, x0, 2.0f);
    k_combine<<<157 * 8, 256, 0, stream>>>(x0, x1, x2, W, bias, out);
}

// Round 7
// 185.193 us; speedup vs baseline: 3.2253x; 1.5259x over previous
//
#include <hip/hip_runtime.h>
#include <hip/hip_fp16.h>

#define N_NODES 10000
#define BATCH   8
#define IN_SZ   64
#define UNITS   64
#define ROW_U   256            // uints per f16 row (512 f16 = 4 stripes of 64)
#define RCAP    96             // fixed per-row edge capacity (P(deg>96) ~ 1e-18)
#define STR     (N_NODES * 64) // uints per stripe (640,000)

typedef unsigned int uint;
typedef unsigned short ushort;
typedef __attribute__((ext_vector_type(8))) _Float16 half8;
typedef __attribute__((ext_vector_type(4))) float float4v;
typedef __attribute__((ext_vector_type(2))) float float2v;

// ---- numeric helpers -------------------------------------------------------
// Edge values bf16-packed (high 16 bits ARE the fp32 bits -> SALU decode).
__device__ inline uint f2bf_bits(float f) {
    uint u = __float_as_uint(f);
    uint r = ((u >> 16) & 1u) + 0x7FFFu;
    return (u + r) >> 16;
}
// x tensors stored as packed fp16 (RNE): enables v_fma_mix_f32 in spmm loop.
__device__ inline uint pack2h(float a, float b) {
    return (uint)__half_as_ushort(__float2half(a)) |
           ((uint)__half_as_ushort(__float2half(b)) << 16);
}
__device__ inline float h_lo(uint u) {
    return __half2float(__ushort_as_half((ushort)(u & 0xFFFFu)));
}
__device__ inline float h_hi(uint u) {
    return __half2float(__ushort_as_half((ushort)(u >> 16)));
}

// ---------------------------------------------------------------------------
// EVIDENCE LEDGER (r1..r6):
//   K (kernel sum) = 106.3us, F (fixed harness) = 75.1us  [r1 vs r5]
//   t_spmm1 = 25.3us (incl. dispatch overhead)            [r6: x5 repeat]
//   Per-dispatch overhead c ~= 12us reconciles ALL data:
//     work ~= {memset .5, T 10, S1 13, S2 15, C 8} + 5c = 106.3  (exact)
//   => ~60us of K is dispatch boundaries. THIS ROUND: fuse spmm2+combine
//   (combine only reads x2 at its OWN rows -> no grid sync needed; x2 lives
//   and dies in LDS). 5 dispatches -> 4; x2 global round-trip eliminated.
// ---------------------------------------------------------------------------

// ---------------------------------------------------------------------------
// k_transpose_scatter: UNCHANGED r1 body. Grid <<<N_NODES, 256>>>.
// ---------------------------------------------------------------------------
__global__ __launch_bounds__(256) void k_transpose_scatter(
    const float2v* __restrict__ in2, uint* __restrict__ x0,
    const int* __restrict__ rows, const int* __restrict__ cols,
    const float* __restrict__ vals, int* __restrict__ cursor,
    uint* __restrict__ edges, int nnz) {
    int gid = blockIdx.x * 256 + threadIdx.x;      // 2,560,000 total
    if (gid < nnz) {
        int r   = rows[gid];
        int pos = r * RCAP + atomicAdd(&cursor[r], 1);
        edges[pos] = (uint)cols[gid] | (f2bf_bits(vals[gid]) << 16);
    }
    int n  = gid >> 8;          // node
    int b  = (gid >> 5) & 7;    // batch
    int iu = gid & 31;
    float2v v = __builtin_nontemporal_load(&in2[(size_t)b * (N_NODES * 32) +
                                                (size_t)n * 32 + iu]);
    int q = (gid >> 6) & 3;     // stripe
    x0[(size_t)q * STR + (size_t)n * 64 + (gid & 63)] = pack2h(v.x, v.y);
}

// ---- spmm inner machinery (shared by k_spmm and the fused kernel) ----------
#define LOADE(EP, OFF)                                                        \
    _Pragma("unroll") for (int jj = 0; jj < 8; ++jj) EP[jj] = edges[(OFF) + jj];

#define GATHERX(XR, EP)                                                       \
    _Pragma("unroll") for (int jj = 0; jj < 8; ++jj) {                        \
        uint c = EP[jj] & 0x3FFFu;                                            \
        if (c > N_NODES - 1) c = N_NODES - 1; /* s_min (poisoned slots) */    \
        XR[jj] = xq[c * 64u + lane];          /* SALU idx + saddr gather */   \
    }

#define FMA8(EP, XR, G0)                                                      \
    _Pragma("unroll") for (int jj = 0; jj < 8; ++jj) {                        \
        uint vb = ((G0) + jj < cnt) ? (EP[jj] & 0xFFFF0000u) : 0u; /* SALU */ \
        float vj = __uint_as_float(vb);                                       \
        a0 += vj * h_lo(XR[jj]); /* v_fma_mix_f32 */                          \
        a1 += vj * h_hi(XR[jj]); /* v_fma_mix_f32 */                          \
    }

#define EDGE_LOOP_BODY()                                                      \
    int nblk = (cnt + 7) >> 3;                                                \
    uint epA[8], epB[8], xA[8], xB[8];                                        \
    LOADE(epA, base);                                                         \
    GATHERX(xA, epA);                                                         \
    int k = 0;                                                                \
    for (; k + 2 <= nblk; k += 2) {                                           \
        LOADE(epB, base + 8 * (k + 1));                                       \
        GATHERX(xB, epB);                                                     \
        FMA8(epA, xA, 8 * k);                                                 \
        if (k + 2 < nblk) {                                                   \
            LOADE(epA, base + 8 * (k + 2));                                   \
            GATHERX(xA, epA);                                                 \
        }                                                                     \
        FMA8(epB, xB, 8 * (k + 1));                                           \
    }                                                                         \
    if (k < nblk) FMA8(epA, xA, 8 * k);

// ---------------------------------------------------------------------------
// k_spmm (spmm1 only now): UNCHANGED r1 semantics, 2-deep pipelined variant.
// Grid <<<N_NODES, 256>>>; stripe q = (L&7)>>1 pinned to XCD pair.
// ---------------------------------------------------------------------------
__global__ __launch_bounds__(256) void k_spmm(const int* __restrict__ cursor,
                                              const uint* __restrict__ edges,
                                              const uint* __restrict__ xin,
                                              uint* __restrict__ xout,
                                              float scale) {
    int L    = blockIdx.x;              // 10000 blocks
    int q    = (L & 7) >> 1;            // stripe pinned to XCD pair {2q,2q+1}
    int rb   = ((L >> 3) << 1) | (L & 1);   // 0..2499, bijective per stripe
    int wave = threadIdx.x >> 6;
    uint lane = threadIdx.x & 63;
    int row  = rb * 4 + wave;

    const uint* xq = xin + (size_t)q * STR;
    int base = row * RCAP;
    int cnt  = __builtin_amdgcn_readfirstlane(cursor[row]);

    float a0 = 0.f, a1 = 0.f;
    EDGE_LOOP_BODY();

    __builtin_nontemporal_store(pack2h(scale * a0, scale * a1),
        &xout[(size_t)q * STR + (size_t)row * 64 + lane]);
}

// ---------------------------------------------------------------------------
// k_spmm2_combine (FUSED): block = (64-node tile mi, stripe q), 512 threads.
//  phase 0: stage weights to LDS (load issues early, hides under phase 1)
//  phase 1: x2[stripe q][rows n0..n0+63] = 2*L x1 - x0  -> LDS x2L[64][68]
//           (8 waves x 8 rows; pad 64->68 dwords: phase-2 LDS reads drop from
//            16-way bank conflict to ~2-way = free per m136)
//  phase 2: combine batches {2q, 2q+1}: wave w -> b = 2q+(w>>2), 16-node tile
//           w&3. af[0..3] from global x0/x1 (XCD-pinned), af[4..5] from x2L.
// x2 never touches global memory; one dispatch boundary eliminated.
// ---------------------------------------------------------------------------
__global__ __launch_bounds__(512) void k_spmm2_combine(
    const int* __restrict__ cursor, const uint* __restrict__ edges,
    const uint* __restrict__ x0, const uint* __restrict__ x1,
    const float* __restrict__ W, const float* __restrict__ bias,
    float* __restrict__ out) {
    __shared__ ushort sWt[64][200];    // [u][k] f16, pad 192->200 (25.6 KB)
    __shared__ uint   x2L[64][68];     // stripe-q x2 tile, padded (17.4 KB)

    int t    = threadIdx.x;
    int wave = t >> 6;
    uint lane = t & 63;
    int L    = blockIdx.x;             // 640 blocks (12 idle)
    int q    = (L & 7) >> 1;           // stripe pinned to XCD pair {2q,2q+1}
    int mi   = ((L >> 3) << 1) | (L & 1);   // 0..159
    if (mi >= 157) return;
    int n0   = mi * 64;

    // ---- phase 0: weight stage (independent of phase 1; issues early) ------
    for (int e = t; e < 192 * 64; e += 512) {
        int f = e >> 6;                // fan_in row = i*3 + m
        int u = e & 63;
        int i = f / 3;
        int m = f - 3 * i;
        sWt[u][m * 64 + i] = __half_as_ushort(__float2half(W[e]));
    }

    // ---- phase 1: spmm2 for this tile's stripe-q rows ----------------------
    {
        const uint* xq = x1 + (size_t)q * STR;
        for (int rr = wave; rr < 64; rr += 8) {
            int row = n0 + rr;
            if (row >= N_NODES) break;
            int base = __builtin_amdgcn_readfirstlane(row * RCAP);
            int cnt  = __builtin_amdgcn_readfirstlane(cursor[row]);
            uint sx = __builtin_nontemporal_load(
                &x0[(size_t)q * STR + (size_t)row * 64 + lane]);
            float a0 = 0.f, a1 = 0.f;
            EDGE_LOOP_BODY();
            x2L[rr][lane] = pack2h(2.f * a0 - h_lo(sx), 2.f * a1 - h_hi(sx));
        }
    }
    __syncthreads();

    // ---- phase 2: combine (MFMA f16), 2 batches x 4 tiles over 8 waves -----
    int mrow = lane & 15, quad = lane >> 4;
    int b    = 2 * q + (wave >> 2);    // batch; b>>1 == q by construction
    int nw0  = n0 + (wave & 3) * 16;
    int an   = nw0 + mrow;
    if (an > N_NODES - 1) an = N_NODES - 1;    // clamp tail reads (stays in tile)

    const uint* xsg[2] = {x0, x1};
    half8 af[6];
#pragma unroll
    for (int kb = 0; kb < 4; ++kb) {   // mats 0,1 from global (XCD-pinned)
        int c_u = b * 32 + (kb & 1) * 16 + quad * 4;
        af[kb] = __builtin_nontemporal_load(
            (const half8*)(xsg[kb >> 1] + (size_t)q * STR + (size_t)an * 64 +
                           (c_u & 63)));
    }
#pragma unroll
    for (int kb = 4; kb < 6; ++kb) {   // mat 2 from LDS
        int c_u = b * 32 + (kb & 1) * 16 + quad * 4;
        af[kb] = *(const half8*)&x2L[an - n0][c_u & 63];
    }

    float4v acc[4];
#pragma unroll
    for (int ut = 0; ut < 4; ++ut) acc[ut] = (float4v){0.f, 0.f, 0.f, 0.f};

#pragma unroll
    for (int kb = 0; kb < 6; ++kb)
#pragma unroll
        for (int ut = 0; ut < 4; ++ut)
            acc[ut] = __builtin_amdgcn_mfma_f32_16x16x32_f16(
                af[kb],
                *(const half8*)&sWt[ut * 16 + mrow][kb * 32 + quad * 8],
                acc[ut], 0, 0, 0);

#pragma unroll
    for (int ut = 0; ut < 4; ++ut) {
        float bv = bias[ut * 16 + mrow];
        int u = ut * 16 + mrow;
#pragma unroll
        for (int r = 0; r < 4; ++r) {
            int n = nw0 + quad * 4 + r;
            if (n < N_NODES)
                __builtin_nontemporal_store(acc[ut][r] + bv,
                    &out[((size_t)b * N_NODES + n) * UNITS + u]);
        }
    }
}

// ---------------------------------------------------------------------------
extern "C" void kernel_launch(void* const* d_in, const int* in_sizes, int n_in,
                              void* d_out, int out_size, void* d_ws, size_t ws_size,
                              hipStream_t stream) {
    const float* inputs = (const float*)d_in[0];
    const int*   rows   = (const int*)d_in[1];
    const int*   cols   = (const int*)d_in[2];
    const float* vals   = (const float*)d_in[3];
    const float* W      = (const float*)d_in[4];
    const float* bias   = (const float*)d_in[5];
    float*       out    = (float*)d_out;
    int nnz = in_sizes[1];

    char* p = (char*)d_ws;
    auto alloc = [&](size_t bytes) {
        char* r = p;
        p += (bytes + 255) & ~(size_t)255;
        return r;
    };
    uint* x0     = (uint*)alloc(sizeof(uint) * (size_t)N_NODES * ROW_U);
    uint* x1     = (uint*)alloc(sizeof(uint) * (size_t)N_NODES * ROW_U);
    int*  cursor = (int*)alloc(sizeof(int) * N_NODES);
    uint* edges  = (uint*)alloc(sizeof(uint) * (size_t)N_NODES * RCAP);

    (void)hipMemsetAsync(cursor, 0, sizeof(int) * N_NODES, stream);
    k_transpose_scatter<<<N_NODES, 256, 0, stream>>>(
        (const float2v*)inputs, x0, rows, cols, vals, cursor, edges, nnz);
    k_spmm<<<N_NODES, 256, 0, stream>>>(cursor, edges, x0, x1, 1.0f);
    k_spmm2_combine<<<640, 512, 0, stream>>>(cursor, edges, x0, x1, W, bias,
                                             out);
}

// Round 8
// 174.935 us; speedup vs baseline: 3.4145x; 1.0586x over previous
//
#include <hip/hip_runtime.h>
#include <hip/hip_fp16.h>

#define N_NODES 10000
#define BATCH   8
#define IN_SZ   64
#define UNITS   64
#define ROW_U   256            // uints per f16 row (512 f16 = 4 stripes of 64)
#define RCAP    96             // fixed per-row edge capacity (P(deg>96) ~ 1e-18)
#define STR     (N_NODES * 64) // uints per stripe (640,000)

typedef unsigned int uint;
typedef unsigned short ushort;
typedef __attribute__((ext_vector_type(8))) _Float16 half8;
typedef __attribute__((ext_vector_type(4))) float float4v;
typedef __attribute__((ext_vector_type(2))) float float2v;

// ---- numeric helpers -------------------------------------------------------
// Edge values bf16-packed (high 16 bits ARE the fp32 bits -> SALU decode).
__device__ inline uint f2bf_bits(float f) {
    uint u = __float_as_uint(f);
    uint r = ((u >> 16) & 1u) + 0x7FFFu;
    return (u + r) >> 16;
}
// x tensors stored as packed fp16 (RNE): enables v_fma_mix_f32 in spmm loop.
__device__ inline uint pack2h(float a, float b) {
    return (uint)__half_as_ushort(__float2half(a)) |
           ((uint)__half_as_ushort(__float2half(b)) << 16);
}
__device__ inline float h_lo(uint u) {
    return __half2float(__ushort_as_half((ushort)(u & 0xFFFFu)));
}
__device__ inline float h_hi(uint u) {
    return __half2float(__ushort_as_half((ushort)(u >> 16)));
}

// ---------------------------------------------------------------------------
// EVIDENCE LEDGER (r1..r7):
//   K = 106.3us, F = 75.1us fixed harness       [r1 vs r5 double-pipeline]
//   t_spmm1 ~= 25.3us REAL GPU time             [r6 x5; graph marginal ~1-2us]
//   Fused S2+C = 53.2us, VALUBusy 28.6%, 20 waves/CU -> TLP collapse [r7]
//   => fusion/persistent structures lose; revert to r1 5-dispatch shape.
//   spmm's 2x gap vs L2-traffic floor (~12us) matches the serial
//   s_load_dwordx8 edge chain through scalar K$ (3.8MB stream, ~300cy
//   misses, 4.2/row). THIS ROUND: edge records via ONE coalesced vector
//   load into a VGPR + v_readlane extraction -- edge path leaves the
//   memory system entirely; only gather latency remains (pipelined).
// ---------------------------------------------------------------------------

// ---------------------------------------------------------------------------
// k_transpose_scatter: UNCHANGED r1 body. Grid <<<N_NODES, 256>>>.
// ---------------------------------------------------------------------------
__global__ __launch_bounds__(256) void k_transpose_scatter(
    const float2v* __restrict__ in2, uint* __restrict__ x0,
    const int* __restrict__ rows, const int* __restrict__ cols,
    const float* __restrict__ vals, int* __restrict__ cursor,
    uint* __restrict__ edges, int nnz) {
    int gid = blockIdx.x * 256 + threadIdx.x;      // 2,560,000 total
    if (gid < nnz) {
        int r   = rows[gid];
        int pos = r * RCAP + atomicAdd(&cursor[r], 1);
        edges[pos] = (uint)cols[gid] | (f2bf_bits(vals[gid]) << 16);
    }
    int n  = gid >> 8;          // node
    int b  = (gid >> 5) & 7;    // batch
    int iu = gid & 31;
    float2v v = __builtin_nontemporal_load(&in2[(size_t)b * (N_NODES * 32) +
                                                (size_t)n * 32 + iu]);
    int q = (gid >> 6) & 3;     // stripe
    x0[(size_t)q * STR + (size_t)n * 64 + (gid & 63)] = pack2h(v.x, v.y);
}

// ---- spmm inner machinery --------------------------------------------------
// Edge block KB (8 edges) extracted from in-register records via v_readlane.
// KB < 8 -> erec (edges 0..63), KB >= 8 -> erec2 (64..95). No straddle (8|64).
#define READE(EP, KB)                                                         \
    {                                                                         \
        uint _es = ((KB) < 8) ? erec : erec2;                                 \
        int  _i0 = (((KB) * 8) & 63);                                         \
        _Pragma("unroll") for (int jj = 0; jj < 8; ++jj)                      \
            EP[jj] = __builtin_amdgcn_readlane(_es, _i0 + jj);                \
    }

#define GATHERX(XR, EP)                                                       \
    _Pragma("unroll") for (int jj = 0; jj < 8; ++jj) {                        \
        uint c = EP[jj] & 0x3FFFu;                                            \
        if (c > N_NODES - 1) c = N_NODES - 1; /* s_min (garbage slots) */     \
        XR[jj] = xq[c * 64u + lane];          /* SALU idx + saddr gather */   \
    }

// val-halves of out-of-count lanes were pre-zeroed -> no per-edge guard.
#define FMA8(EP, XR)                                                          \
    _Pragma("unroll") for (int jj = 0; jj < 8; ++jj) {                        \
        float vj = __uint_as_float(EP[jj] & 0xFFFF0000u); /* SALU decode */   \
        a0 += vj * h_lo(XR[jj]); /* v_fma_mix_f32 */                          \
        a1 += vj * h_hi(XR[jj]); /* v_fma_mix_f32 */                          \
    }

// ---------------------------------------------------------------------------
// k_spmm: one WAVE per (row, stripe); lane owns one uint (2 fp16 cols).
// Edge records: ONE coalesced vector load (256B = whole 64-slot bucket) into
// erec; per-edge extraction is v_readlane (register-only). Tail masking: one
// v_cndmask zeroes val-halves of lanes >= cnt (contribution becomes +0.0).
// Grid <<<N_NODES, 256>>>; stripe q = (L&7)>>1 pinned to XCD pair {2q,2q+1}.
// ---------------------------------------------------------------------------
__global__ __launch_bounds__(256) void k_spmm(const int* __restrict__ cursor,
                                              const uint* __restrict__ edges,
                                              const uint* __restrict__ xin,
                                              uint* __restrict__ xout,
                                              const uint* __restrict__ xsub,
                                              float scale) {
    int L    = blockIdx.x;              // 10000 blocks
    int q    = (L & 7) >> 1;            // stripe pinned to XCD pair {2q,2q+1}
    int rb   = ((L >> 3) << 1) | (L & 1);   // 0..2499, bijective per stripe
    int wave = threadIdx.x >> 6;
    uint lane = threadIdx.x & 63;
    int row  = rb * 4 + wave;

    const uint* xq = xin + (size_t)q * STR;
    int base = row * RCAP;
    int cnt  = __builtin_amdgcn_readfirstlane(cursor[row]);
    int nblk = (cnt + 7) >> 3;          // >= 1 (diagonal guarantees cnt >= 1)

    // edge records 0..63 in one coalesced 256B vector load; mask val-half of
    // lanes >= cnt (they then contribute exactly +0.0 in FMA8).
    uint erec = edges[base + (int)lane];
    if ((int)lane >= cnt) erec &= 0x3FFFu;          // v_cndmask
    uint erec2 = 0;
    if (cnt > 64) {                                  // uniform branch, rare
        erec2 = edges[base + 64 + (int)lane];
        if ((int)lane + 64 >= cnt) erec2 &= 0x3FFFu;
    }

    // hoisted subtract operand: latency hides under the edge loop
    uint sx = 0;
    if (xsub) sx = __builtin_nontemporal_load(
        &xsub[(size_t)q * STR + (size_t)row * 64 + lane]);

    float a0 = 0.f, a1 = 0.f;
    uint epA[8], epB[8], xA[8], xB[8];
    READE(epA, 0);
    GATHERX(xA, epA);
    int k = 0;
    for (; k + 2 <= nblk; k += 2) {
        READE(epB, k + 1);                // register-only: no lgkm chain
        GATHERX(xB, epB);                 // gathers in flight
        FMA8(epA, xA);                    // consume stage k
        if (k + 2 < nblk) {
            READE(epA, k + 2);
            GATHERX(xA, epA);
        }
        FMA8(epB, xB);                    // consume stage k+1
    }
    if (k < nblk) FMA8(epA, xA);          // odd block count

    float o0 = scale * a0, o1 = scale * a1;
    if (xsub) {
        o0 -= h_lo(sx);
        o1 -= h_hi(sx);
    }
    __builtin_nontemporal_store(pack2h(o0, o1),
        &xout[(size_t)q * STR + (size_t)row * 64 + lane]);
}

// ---------------------------------------------------------------------------
// k_combine (MFMA f16): UNCHANGED r1 body. Grid <<<157*8, 256>>>;
// b = L&7 pins batch -> stripe q=b>>1 stays on XCD pair {2q,2q+1}.
// ---------------------------------------------------------------------------
__global__ __launch_bounds__(256) void k_combine(const uint* __restrict__ x0,
                                                 const uint* __restrict__ x1,
                                                 const uint* __restrict__ x2,
                                                 const float* __restrict__ W,
                                                 const float* __restrict__ bias,
                                                 float* __restrict__ out) {
    __shared__ ushort sWt[64][200];    // [u][k] f16, pad 192->200 (25.6 KB)
    int t = threadIdx.x;
    for (int e = t; e < 192 * 64; e += 256) {
        int f = e >> 6;                // fan_in row = i*3 + m
        int u = e & 63;
        int i = f / 3;
        int m = f - 3 * i;
        sWt[u][m * 64 + i] = __half_as_ushort(__float2half(W[e]));
    }
    __syncthreads();

    int wave = t >> 6, lane = t & 63;
    int mrow = lane & 15, quad = lane >> 4;
    int L    = blockIdx.x;
    int b    = L & 7;                  // XCD-pinned batch -> stripe b>>1
    int n0   = (L >> 3) * 64 + wave * 16;

    const uint* xs[3] = {x0, x1, x2};
    int an = n0 + mrow;
    if (an > N_NODES - 1) an = N_NODES - 1;    // clamp tail reads

    half8 af[6];
#pragma unroll
    for (int kb = 0; kb < 6; ++kb) {
        int mat = kb >> 1;
        int c_u = b * 32 + (kb & 1) * 16 + quad * 4;      // column uint index
        int q   = c_u >> 6;                               // = b>>1
        af[kb] = __builtin_nontemporal_load(
            (const half8*)(xs[mat] + (size_t)q * STR + (size_t)an * 64 +
                           (c_u & 63)));
    }

    float4v acc[4];
#pragma unroll
    for (int ut = 0; ut < 4; ++ut) acc[ut] = (float4v){0.f, 0.f, 0.f, 0.f};

#pragma unroll
    for (int kb = 0; kb < 6; ++kb)
#pragma unroll
        for (int ut = 0; ut < 4; ++ut)
            acc[ut] = __builtin_amdgcn_mfma_f32_16x16x32_f16(
                af[kb],
                *(const half8*)&sWt[ut * 16 + mrow][kb * 32 + quad * 8],
                acc[ut], 0, 0, 0);

#pragma unroll
    for (int ut = 0; ut < 4; ++ut) {
        float bv = bias[ut * 16 + mrow];
        int u = ut * 16 + mrow;
#pragma unroll
        for (int r = 0; r < 4; ++r) {
            int n = n0 + quad * 4 + r;
            if (n < N_NODES)
                __builtin_nontemporal_store(acc[ut][r] + bv,
                    &out[((size_t)b * N_NODES + n) * UNITS + u]);
        }
    }
}

// ---------------------------------------------------------------------------
extern "C" void kernel_launch(void* const* d_in, const int* in_sizes, int n_in,
                              void* d_out, int out_size, void* d_ws, size_t ws_size,
                              hipStream_t stream) {
    const float* inputs = (const float*)d_in[0];
    const int*   rows   = (const int*)d_in[1];
    const int*   cols   = (const int*)d_in[2];
    const float* vals   = (const float*)d_in[3];
    const float* W      = (const float*)d_in[4];
    const float* bias   = (const float*)d_in[5];
    float*       out    = (float*)d_out;
    int nnz = in_sizes[1];

    char* p = (char*)d_ws;
    auto alloc = [&](size_t bytes) {
        char* r = p;
        p += (bytes + 255) & ~(size_t)255;
        return r;
    };
    uint* x0     = (uint*)alloc(sizeof(uint) * (size_t)N_NODES * ROW_U);
    uint* x1     = (uint*)alloc(sizeof(uint) * (size_t)N_NODES * ROW_U);
    uint* x2     = (uint*)alloc(sizeof(uint) * (size_t)N_NODES * ROW_U);
    int*  cursor = (int*)alloc(sizeof(int) * N_NODES);
    // +128 uints pad: erec2 read (base+64+lane) of the last row stays in-bounds
    uint* edges  = (uint*)alloc(sizeof(uint) * ((size_t)N_NODES * RCAP + 128));

    (void)hipMemsetAsync(cursor, 0, sizeof(int) * N_NODES, stream);
    k_transpose_scatter<<<N_NODES, 256, 0, stream>>>(
        (const float2v*)inputs, x0, rows, cols, vals, cursor, edges, nnz);
    k_spmm<<<N_NODES, 256, 0, stream>>>(cursor, edges, x0, x1, nullptr, 1.0f);
    k_spmm<<<N_NODES, 256, 0, stream>>>(cursor, edges, x1, x2, x0, 2.0f);
    k_combine<<<157 * 8, 256, 0, stream>>>(x0, x1, x2, W, bias, out);
}